// Round 8
// baseline (233.240 us; speedup 1.0000x reference)
//
#include <hip/hip_runtime.h>
#include <hip/hip_bf16.h>

#define N_NODES 10000
#define C_DIM   256
#define H_HEADS 8
#define D_HEAD  32
#define E_EDGES 320000
#define L_LAYERS 3
#define GN      1024   // fused q|kv-paired|skip output width

typedef __attribute__((ext_vector_type(8))) short bf16x8;
typedef __attribute__((ext_vector_type(4))) float f32x4;

__device__ __forceinline__ unsigned short f2b(float f) {
  __hip_bfloat16 h = __float2bfloat16(f);
  return *(unsigned short*)&h;
}

__device__ __forceinline__ float kv_lo(unsigned int w) {  // low ushort as bf16
  union { unsigned int u; float f; } c; c.u = w << 16; return c.f;
}
__device__ __forceinline__ float kv_hi(unsigned int w) {  // high ushort as bf16
  union { unsigned int u; float f; } c; c.u = w & 0xffff0000u; return c.f;
}

__device__ __forceinline__ void gload16(const void* g, void* l) {
  __builtin_amdgcn_global_load_lds(
      (const __attribute__((address_space(1))) unsigned int*)g,
      (__attribute__((address_space(3))) unsigned int*)l, 16, 0, 0);
}

// fused-column map: q -> c, k -> 256+(c>>6)*128+(c&63), v -> +64, s -> 768+c
__device__ __forceinline__ int colmap(int mat, int c) {
  if (mat == 0) return c;
  if (mat == 3) return 768 + c;
  return 256 + ((c >> 6) << 7) + ((mat - 1) << 6) + (c & 63);
}

// ---------------- CSR build (dst -> list of src) ----------------
__global__ void hist_kernel(const int* __restrict__ dst, int* __restrict__ deg) {
  int e = blockIdx.x * blockDim.x + threadIdx.x;
  if (e < E_EDGES) atomicAdd(&deg[dst[e]], 1);
}

__global__ __launch_bounds__(1024) void scan_kernel(const int* __restrict__ deg,
                                                    int* __restrict__ row_ptr) {
  __shared__ int part[1024];
  int t = threadIdx.x;
  const int CHUNK = (N_NODES + 1023) / 1024;  // 10
  int base = t * CHUNK;
  int s = 0;
  for (int i = 0; i < CHUNK; ++i) {
    int idx = base + i;
    if (idx < N_NODES) s += deg[idx];
  }
  part[t] = s;
  __syncthreads();
  for (int off = 1; off < 1024; off <<= 1) {
    int v = (t >= off) ? part[t - off] : 0;
    __syncthreads();
    part[t] += v;
    __syncthreads();
  }
  int run = (t == 0) ? 0 : part[t - 1];
  for (int i = 0; i < CHUNK; ++i) {
    int idx = base + i;
    if (idx <= N_NODES) {
      row_ptr[idx] = run;
      if (idx < N_NODES) run += deg[idx];
    }
  }
}

__global__ void scatter_kernel(const int* __restrict__ src, const int* __restrict__ dst,
                               const int* __restrict__ row_ptr, int* __restrict__ fill,
                               int* __restrict__ srcs) {
  int e = blockIdx.x * blockDim.x + threadIdx.x;
  if (e < E_EDGES) {
    int d = dst[e];
    int pos = atomicAdd(&fill[d], 1);
    srcs[row_ptr[d] + pos] = src[e];
  }
}

// ---------------- fused one-time converts (x, W, b) ----------------
// blocks [0,2500): convx; [2500,3268): convw tiles; [3268,3281): convb
__global__ __launch_bounds__(256) void conv_all_kernel(
    const float* __restrict__ x, __hip_bfloat16* __restrict__ xb,
    const float* __restrict__ Wq, const float* __restrict__ Wk,
    const float* __restrict__ Wv, const float* __restrict__ Ws,
    __hip_bfloat16* __restrict__ Wt,
    const float* __restrict__ bq, const float* __restrict__ bk,
    const float* __restrict__ bv, const float* __restrict__ bs,
    float* __restrict__ biasf) {
  __shared__ float tt[32][33];
  int b = blockIdx.x, t = threadIdx.x;
  if (b < 2500) {
    int i = b * 256 + t;  // one per 4 elems, 640000 total
    float4 f = *(const float4*)&x[(size_t)i * 4];
    union { unsigned short u[4]; uint2 w; } o;
    o.u[0] = f2b(f.x); o.u[1] = f2b(f.y); o.u[2] = f2b(f.z); o.u[3] = f2b(f.w);
    *(uint2*)&xb[(size_t)i * 4] = o.w;
  } else if (b < 3268) {
    int zz = b - 2500;          // 768 tiles
    int z = zz >> 6, tile = zz & 63;
    int l = z >> 2, mat = z & 3;
    const float* W = (mat == 0 ? Wq : mat == 1 ? Wk : mat == 2 ? Wv : Ws)
                     + (size_t)l * C_DIM * C_DIM;
    int k0 = (tile >> 3) * 32, c0 = (tile & 7) * 32;
    int tx = t & 31, ty = t >> 5;
    for (int i = 0; i < 32; i += 8)
      tt[ty + i][tx] = W[(k0 + ty + i) * C_DIM + c0 + tx];
    __syncthreads();
    for (int i = 0; i < 32; i += 8) {
      int ncol = colmap(mat, c0 + ty + i);
      Wt[(size_t)l * GN * C_DIM + (size_t)ncol * C_DIM + k0 + tx] =
          __float2bfloat16(tt[tx][ty + i]);
    }
  } else {
    int i = (b - 3268) * 256 + t;
    if (i < L_LAYERS * GN) {
      int l = i >> 10, n = i & 1023;
      int mat = n >> 8, c = n & 255;
      const float* bb = (mat == 0 ? bq : mat == 1 ? bk : mat == 2 ? bv : bs);
      biasf[l * GN + colmap(mat, c)] = bb[l * C_DIM + c];
    }
  }
}

// ---------------- bf16 MFMA GEMM: [10000,256] @ Wt^T -> q|k|v|skip ----------------
// 128x128 tile, BK=64, 256 threads (4 waves 2x2), LDS XOR-swizzled (T2 both-sides).
// kv blocks (col0 in [256,768)) stage a DE-INTERLEAVED [row][k64|v64] tile in LDS
// and store 128B k-rows to k2 and v-rows to v2 ([2][N][128] bf16 each -> 2.56MB
// per slice, L2-resident for the phase-split aggregation).
// q blocks store into [2][N][128] fp32 (slice = channel>>7).
__global__ __launch_bounds__(256) void gemm_kernel(
    const __hip_bfloat16* __restrict__ xb,   // [10000][256]
    const __hip_bfloat16* __restrict__ Wt,   // [1024][256] (this layer, col-paired)
    const float* __restrict__ biasf,         // [1024] (col-paired)
    float* __restrict__ q2,                  // [2][N][128] fp32
    unsigned short* __restrict__ k2,         // [2][N][128] bf16
    unsigned short* __restrict__ v2,         // [2][N][128] bf16
    float* __restrict__ skip) {              // [N][256] fp32
  __shared__ __align__(16) unsigned short SH[16384];  // 32KB: As|Bs, reused for kv tile
  __hip_bfloat16* As = (__hip_bfloat16*)SH;
  __hip_bfloat16* Bs = (__hip_bfloat16*)(SH + 8192);
  int tid = threadIdx.x;
  int wid = tid >> 6, lane = tid & 63;
  int row0 = blockIdx.x * 128;
  int col0 = blockIdx.y * 128;
  int wr = wid >> 1, wc = wid & 1;
  int lr = lane & 15, lq = lane >> 4;
  int swz = (lr & 7) * 8;  // read-side XOR (elements)

  f32x4 acc[4][4] = {};

  for (int k0 = 0; k0 < C_DIM; k0 += 64) {
#pragma unroll
    for (int j = 0; j < 4; ++j) {
      int c = j * 256 + wid * 64 + lane;
      int arow = c >> 3;
      int kc = 8 * ((c & 7) ^ ((c >> 3) & 7));  // inverse-swizzled source
      int grow = row0 + arow;
      if (grow > N_NODES - 1) grow = N_NODES - 1;  // clamp: in-bounds, rows unused
      gload16(xb + (size_t)grow * C_DIM + k0 + kc, As + (size_t)(j * 256 + wid * 64) * 8);
    }
#pragma unroll
    for (int j = 0; j < 4; ++j) {
      int c = j * 256 + wid * 64 + lane;
      int brow = c >> 3;
      int kc = 8 * ((c & 7) ^ ((c >> 3) & 7));
      gload16(Wt + (size_t)(col0 + brow) * C_DIM + k0 + kc,
              Bs + (size_t)(j * 256 + wid * 64) * 8);
    }
    __syncthreads();

#pragma unroll
    for (int ks = 0; ks < 2; ++ks) {
      bf16x8 fa[4], fb[4];
#pragma unroll
      for (int m = 0; m < 4; ++m)
        fa[m] = *(const bf16x8*)&As[(wr * 64 + m * 16 + lr) * 64 + ((ks * 32 + lq * 8) ^ swz)];
#pragma unroll
      for (int n = 0; n < 4; ++n)
        fb[n] = *(const bf16x8*)&Bs[(wc * 64 + n * 16 + lr) * 64 + ((ks * 32 + lq * 8) ^ swz)];
#pragma unroll
      for (int m = 0; m < 4; ++m)
#pragma unroll
        for (int n = 0; n < 4; ++n)
          acc[m][n] = __builtin_amdgcn_mfma_f32_16x16x32_bf16(fa[m], fb[n], acc[m][n], 0, 0, 0);
    }
    __syncthreads();
  }

  float bias_n[4];
#pragma unroll
  for (int n = 0; n < 4; ++n) bias_n[n] = biasf[col0 + wc * 64 + n * 16 + lr];

  if (col0 >= 256 && col0 < 768) {
    // ---- kv path: stage de-interleaved [row][k64|v64] tile, then 128B row stores
    int half = wc;  // wc=0 -> k cols, wc=1 -> v cols (column pairing)
#pragma unroll
    for (int m = 0; m < 4; ++m) {
#pragma unroll
      for (int n = 0; n < 4; ++n) {
        int chs = n * 16 + lr;  // channel-in-64-block 0..63
#pragma unroll
        for (int r = 0; r < 4; ++r) {
          int row = wr * 64 + m * 16 + lq * 4 + r;
          SH[row * 128 + half * 64 + chs] = f2b(acc[m][n][r] + bias_n[n]);
        }
      }
    }
    __syncthreads();
    int bl = (col0 - 256) >> 7;   // 64-ch k-group 0..3
    int sl = bl >> 1;             // slice 0..1
    int h64 = (bl & 1) * 64;      // 64-ch half within 128-ch slice
    int t16 = tid & 15, rbase = tid >> 4;
#pragma unroll
    for (int it = 0; it < 8; ++it) {
      int row = it * 16 + rbase;
      int grow = row0 + row;
      if (grow < N_NODES) {
        uint4 vv = *(const uint4*)&SH[row * 128 + t16 * 8];  // 8 ch
        size_t base = ((size_t)sl * N_NODES + grow) * 128 + h64;
        unsigned short* dp = (t16 < 8) ? (k2 + base + t16 * 8)
                                       : (v2 + base + (t16 - 8) * 8);
        *(uint4*)dp = vv;
      }
    }
  } else {
    // ---- q / skip scalar path
#pragma unroll
    for (int m = 0; m < 4; ++m) {
#pragma unroll
      for (int n = 0; n < 4; ++n) {
        int colG = col0 + wc * 64 + n * 16 + lr;
#pragma unroll
        for (int r = 0; r < 4; ++r) {
          int grow = row0 + wr * 64 + m * 16 + lq * 4 + r;
          if (grow < N_NODES) {
            float val = acc[m][n][r] + bias_n[n];
            if (col0 < 256) {
              q2[((size_t)(colG >> 7) * N_NODES + grow) * 128 + (colG & 127)] = val;
            } else {
              skip[(size_t)grow * C_DIM + (colG - 768)] = val;
            }
          }
        }
      }
    }
  }
}

// ---------------- phase A: scores (k-only gather, L2-resident 2.56MB/slice) ----
// Wave = (dst node, 128-ch k-slice). 16 lanes/edge (8 ch/lane), 4 edges per
// gather instruction (slot = lane>>4). head = 4 lanes (32 ch). Computes
// e = exp2(q.k * log2e/sqrt(32)) per (edge, head); streams esc[E][4] fp32 and
// per-node denom. slice = blockIdx&1 -> XCD parity pinning. No-max softmax is
// exact (|s| small, shift-invariance). Depth-2 pipeline, fully predicated.
__global__ __launch_bounds__(256) void score_kernel(
    const float* __restrict__ q2,          // [2][N][128] fp32
    const unsigned short* __restrict__ k2, // [2][N][128] bf16
    const int* __restrict__ row_ptr, const int* __restrict__ srcs,
    float* __restrict__ esc,               // [2][E][4] fp32
    float* __restrict__ dnm) {             // [2][N][4] fp32
  int b = blockIdx.x;
  int slice = b & 1;
  int wid = threadIdx.x >> 6, lane = threadIdx.x & 63;
  int n = (b >> 1) * 4 + wid;
  int slot = lane >> 4;                    // 4 edge-slots
  int le = lane & 15;                      // ch-position (8 ch each)
  int h = le >> 2;                         // head-in-slice 0..3
  const float scl = 0.25503526f;           // log2(e)/sqrt(32)
  const unsigned short* ks = k2 + (size_t)slice * N_NODES * 128;
  float* escS = esc + (size_t)slice * E_EDGES * 4;

  const float* qrow = &q2[((size_t)slice * N_NODES + n) * 128 + le * 8];
  float4 qa = *(const float4*)qrow;
  float4 qb = *(const float4*)(qrow + 4);
  qa.x *= scl; qa.y *= scl; qa.z *= scl; qa.w *= scl;
  qb.x *= scl; qb.y *= scl; qb.z *= scl; qb.w *= scl;

  int beg = row_ptr[n], end = row_ptr[n + 1];
  float l = 0.f;

  if (beg < end) {
    int j0 = beg + slot;
    int sc = srcs[j0 < end ? j0 : beg];
    uint4 w = *(const uint4*)&ks[(size_t)sc * 128 + le * 8];
    int j1 = beg + 4 + slot;
    int sn = srcs[j1 < end ? j1 : beg];
    for (int i = beg; i < end; i += 4) {
      uint4 wn = w;
      bool more = (i + 4) < end;
      if (more) {                          // issue t+1 gather + t+2 index
        wn = *(const uint4*)&ks[(size_t)sn * 128 + le * 8];
        int j2 = i + 8 + slot;
        sn = srcs[j2 < end ? j2 : beg];
      }
      float p = fmaf(qa.x, kv_lo(w.x), fmaf(qa.y, kv_hi(w.x),
                fmaf(qa.z, kv_lo(w.y), fmaf(qa.w, kv_hi(w.y),
                fmaf(qb.x, kv_lo(w.z), fmaf(qb.y, kv_hi(w.z),
                fmaf(qb.z, kv_lo(w.w), qb.w * kv_hi(w.w))))))));
      p += __shfl_xor(p, 1);               // reduce 4 lanes = 32 ch (one head)
      p += __shfl_xor(p, 2);
      bool valid = (i + slot) < end;
      float e = valid ? exp2f(p) : 0.f;
      l += e;
      if (valid && (lane & 3) == 0)
        escS[(size_t)(i + slot) * 4 + h] = e;   // 16 writers, contiguous 64B
      w = wn;
    }
  }
  l += __shfl_xor(l, 16);                  // sum the 4 slots
  l += __shfl_xor(l, 32);
  if (lane < 16 && (lane & 3) == 0)
    dnm[((size_t)slice * N_NODES + n) * 4 + h] = l;
}

// ---------------- phase B: aggregate (v-only gather, L2-resident 2.56MB/slice) --
// Same geometry as phase A. Reads the contiguous esc stream, accumulates
// sum(e * v) per channel, scales once by 1/denom at the end, writes out and
// bf16 xb for the next layer.
__global__ __launch_bounds__(256) void aggr_kernel(
    const unsigned short* __restrict__ v2, // [2][N][128] bf16
    const float* __restrict__ esc,         // [2][E][4] fp32
    const float* __restrict__ dnm,         // [2][N][4] fp32
    const int* __restrict__ row_ptr, const int* __restrict__ srcs,
    float* __restrict__ out, __hip_bfloat16* __restrict__ xb_next) {
  int b = blockIdx.x;
  int slice = b & 1;
  int wid = threadIdx.x >> 6, lane = threadIdx.x & 63;
  int n = (b >> 1) * 4 + wid;
  int slot = lane >> 4;
  int le = lane & 15;
  int h = le >> 2;
  const unsigned short* vs = v2 + (size_t)slice * N_NODES * 128;
  const float* escS = esc + (size_t)slice * E_EDGES * 4;

  float inv = 1.f / (dnm[((size_t)slice * N_NODES + n) * 4 + h] + 1e-16f);

  int beg = row_ptr[n], end = row_ptr[n + 1];
  float a0 = 0.f, a1 = 0.f, a2 = 0.f, a3 = 0.f;
  float a4 = 0.f, a5 = 0.f, a6 = 0.f, a7 = 0.f;

  if (beg < end) {
    int j0 = beg + slot;
    int jc = j0 < end ? j0 : beg;
    int sc = srcs[jc];
    uint4 w = *(const uint4*)&vs[(size_t)sc * 128 + le * 8];
    float ec = escS[(size_t)jc * 4 + h];
    int j1 = beg + 4 + slot;
    int jn = j1 < end ? j1 : beg;
    int sn = srcs[jn];
    for (int i = beg; i < end; i += 4) {
      uint4 wn = w; float en = 0.f;
      bool more = (i + 4) < end;
      if (more) {                          // issue t+1 gather + esc, t+2 index
        wn = *(const uint4*)&vs[(size_t)sn * 128 + le * 8];
        en = escS[(size_t)jn * 4 + h];
        int j2 = i + 8 + slot;
        jn = j2 < end ? j2 : beg;
        sn = srcs[jn];
      }
      float e = ((i + slot) < end) ? ec : 0.f;
      a0 = fmaf(e, kv_lo(w.x), a0);
      a1 = fmaf(e, kv_hi(w.x), a1);
      a2 = fmaf(e, kv_lo(w.y), a2);
      a3 = fmaf(e, kv_hi(w.y), a3);
      a4 = fmaf(e, kv_lo(w.z), a4);
      a5 = fmaf(e, kv_hi(w.z), a5);
      a6 = fmaf(e, kv_lo(w.w), a6);
      a7 = fmaf(e, kv_hi(w.w), a7);
      w = wn; ec = en;
    }
  }
  // sum the 4 slots
  a0 += __shfl_xor(a0, 16); a0 += __shfl_xor(a0, 32);
  a1 += __shfl_xor(a1, 16); a1 += __shfl_xor(a1, 32);
  a2 += __shfl_xor(a2, 16); a2 += __shfl_xor(a2, 32);
  a3 += __shfl_xor(a3, 16); a3 += __shfl_xor(a3, 32);
  a4 += __shfl_xor(a4, 16); a4 += __shfl_xor(a4, 32);
  a5 += __shfl_xor(a5, 16); a5 += __shfl_xor(a5, 32);
  a6 += __shfl_xor(a6, 16); a6 += __shfl_xor(a6, 32);
  a7 += __shfl_xor(a7, 16); a7 += __shfl_xor(a7, 32);

  if (lane < 16) {
    size_t idx = (size_t)n * C_DIM + slice * 128 + le * 8;
    float4 o1 = *(const float4*)&out[idx];
    float4 o2 = *(const float4*)&out[idx + 4];
    o1.x += a0 * inv; o1.y += a1 * inv; o1.z += a2 * inv; o1.w += a3 * inv;
    o2.x += a4 * inv; o2.y += a5 * inv; o2.z += a6 * inv; o2.w += a7 * inv;
    *(float4*)&out[idx] = o1;
    *(float4*)&out[idx + 4] = o2;
    union { unsigned short us[8]; uint4 w; } ob;
    ob.us[0] = f2b(o1.x); ob.us[1] = f2b(o1.y); ob.us[2] = f2b(o1.z); ob.us[3] = f2b(o1.w);
    ob.us[4] = f2b(o2.x); ob.us[5] = f2b(o2.y); ob.us[6] = f2b(o2.z); ob.us[7] = f2b(o2.w);
    *(uint4*)&xb_next[idx] = ob.w;
  }
}

extern "C" void kernel_launch(void* const* d_in, const int* in_sizes, int n_in,
                              void* d_out, int out_size, void* d_ws, size_t ws_size,
                              hipStream_t stream) {
  const float* x0 = (const float*)d_in[0];
  const float* Wq = (const float*)d_in[1];
  const float* bq = (const float*)d_in[2];
  const float* Wk = (const float*)d_in[3];
  const float* bk = (const float*)d_in[4];
  const float* Wv = (const float*)d_in[5];
  const float* bv = (const float*)d_in[6];
  const float* Ws = (const float*)d_in[7];
  const float* bs = (const float*)d_in[8];
  const int* ei  = (const int*)d_in[9];
  const int* src = ei;
  const int* dst = ei + E_EDGES;
  float* out = (float*)d_out;

  const size_t NC = (size_t)N_NODES * C_DIM;  // 2,560,000 (= 2*N*128)
  __hip_bfloat16* xb = (__hip_bfloat16*)d_ws;
  unsigned short* k2 = (unsigned short*)(xb + NC);      // [2][N][128] bf16
  unsigned short* v2 = k2 + NC;                         // [2][N][128] bf16
  __hip_bfloat16* Wt = (__hip_bfloat16*)(v2 + NC);      // 3*1024*256
  float* qbuf  = (float*)(Wt + (size_t)L_LAYERS * GN * C_DIM);  // [2][N][128]
  float* skipA = qbuf + NC;
  float* biasf = skipA + NC;                            // 3*1024
  float* esc   = biasf + L_LAYERS * GN;                 // [2][E][4] fp32
  float* dnm   = esc + (size_t)2 * E_EDGES * 4;         // [2][N][4] fp32
  int* row_ptr = (int*)(dnm + (size_t)2 * N_NODES * 4);
  int* deg  = row_ptr + (N_NODES + 1);
  int* fill = deg + N_NODES;
  int* srcs = fill + N_NODES;

  (void)hipMemsetAsync(deg, 0, 2 * N_NODES * sizeof(int), stream);  // deg + fill
  hist_kernel<<<(E_EDGES + 255) / 256, 256, 0, stream>>>(dst, deg);
  scan_kernel<<<1, 1024, 0, stream>>>(deg, row_ptr);
  scatter_kernel<<<(E_EDGES + 255) / 256, 256, 0, stream>>>(src, dst, row_ptr, fill, srcs);

  conv_all_kernel<<<3281, 256, 0, stream>>>(x0, xb, Wq, Wk, Wv, Ws, Wt,
                                            bq, bk, bv, bs, biasf);

  for (int l = 0; l < L_LAYERS; ++l) {
    float* skip = (l == L_LAYERS - 1) ? out : skipA;
    gemm_kernel<<<dim3((N_NODES + 127) / 128, GN / 128), 256, 0, stream>>>(
        xb, Wt + (size_t)l * GN * C_DIM, biasf + l * GN, qbuf, k2, v2, skip);
    score_kernel<<<dim3(2 * (N_NODES / 4)), 256, 0, stream>>>(
        qbuf, k2, row_ptr, srcs, esc, dnm);
    aggr_kernel<<<dim3(2 * (N_NODES / 4)), 256, 0, stream>>>(
        v2, esc, dnm, row_ptr, srcs, skip, xb);
  }
}

// Round 9
// 223.508 us; speedup vs baseline: 1.0435x; 1.0435x over previous
//
#include <hip/hip_runtime.h>
#include <hip/hip_bf16.h>

#define N_NODES 10000
#define C_DIM   256
#define H_HEADS 8
#define D_HEAD  32
#define E_EDGES 320000
#define L_LAYERS 3
#define GN      1024   // fused q|kv-paired|skip output width

typedef __attribute__((ext_vector_type(8))) short bf16x8;
typedef __attribute__((ext_vector_type(4))) float f32x4;

__device__ __forceinline__ unsigned short f2b(float f) {
  __hip_bfloat16 h = __float2bfloat16(f);
  return *(unsigned short*)&h;
}

__device__ __forceinline__ float kv_lo(unsigned int w) {  // k in low ushort
  union { unsigned int u; float f; } c; c.u = w << 16; return c.f;
}
__device__ __forceinline__ float kv_hi(unsigned int w) {  // v in high ushort
  union { unsigned int u; float f; } c; c.u = w & 0xffff0000u; return c.f;
}

__device__ __forceinline__ float red8(float p) {  // sum over 8-lane group (one head)
  p += __shfl_xor(p, 1);
  p += __shfl_xor(p, 2);
  p += __shfl_xor(p, 4);
  return p;
}

__device__ __forceinline__ float dot4(float4 q, uint4 w) {
  return fmaf(q.x, kv_lo(w.x),
         fmaf(q.y, kv_lo(w.y),
         fmaf(q.z, kv_lo(w.z), q.w * kv_lo(w.w))));
}

__device__ __forceinline__ void gload16(const void* g, void* l) {
  __builtin_amdgcn_global_load_lds(
      (const __attribute__((address_space(1))) unsigned int*)g,
      (__attribute__((address_space(3))) unsigned int*)l, 16, 0, 0);
}

// fused-column map: q -> c, k -> 256+(c>>6)*128+(c&63), v -> +64, s -> 768+c
__device__ __forceinline__ int colmap(int mat, int c) {
  if (mat == 0) return c;
  if (mat == 3) return 768 + c;
  return 256 + ((c >> 6) << 7) + ((mat - 1) << 6) + (c & 63);
}

// ---------------- CSR build (dst -> list of src) ----------------
__global__ void hist_kernel(const int* __restrict__ dst, int* __restrict__ deg) {
  int e = blockIdx.x * blockDim.x + threadIdx.x;
  if (e < E_EDGES) atomicAdd(&deg[dst[e]], 1);
}

__global__ __launch_bounds__(1024) void scan_kernel(const int* __restrict__ deg,
                                                    int* __restrict__ row_ptr) {
  __shared__ int part[1024];
  int t = threadIdx.x;
  const int CHUNK = (N_NODES + 1023) / 1024;  // 10
  int base = t * CHUNK;
  int s = 0;
  for (int i = 0; i < CHUNK; ++i) {
    int idx = base + i;
    if (idx < N_NODES) s += deg[idx];
  }
  part[t] = s;
  __syncthreads();
  for (int off = 1; off < 1024; off <<= 1) {
    int v = (t >= off) ? part[t - off] : 0;
    __syncthreads();
    part[t] += v;
    __syncthreads();
  }
  int run = (t == 0) ? 0 : part[t - 1];
  for (int i = 0; i < CHUNK; ++i) {
    int idx = base + i;
    if (idx <= N_NODES) {
      row_ptr[idx] = run;
      if (idx < N_NODES) run += deg[idx];
    }
  }
}

// srcs stores BYTE OFFSETS into a kv slice (src * 512 = src*128ch*4B) so the
// agg gather needs no per-edge shift/mul.
__global__ void scatter_kernel(const int* __restrict__ src, const int* __restrict__ dst,
                               const int* __restrict__ row_ptr, int* __restrict__ fill,
                               int* __restrict__ srcs) {
  int e = blockIdx.x * blockDim.x + threadIdx.x;
  if (e < E_EDGES) {
    int d = dst[e];
    int pos = atomicAdd(&fill[d], 1);
    srcs[row_ptr[d] + pos] = src[e] << 9;
  }
}

// ---------------- fused one-time converts (x, W, b) ----------------
// blocks [0,2500): convx; [2500,3268): convw tiles; [3268,3281): convb
__global__ __launch_bounds__(256) void conv_all_kernel(
    const float* __restrict__ x, __hip_bfloat16* __restrict__ xb,
    const float* __restrict__ Wq, const float* __restrict__ Wk,
    const float* __restrict__ Wv, const float* __restrict__ Ws,
    __hip_bfloat16* __restrict__ Wt,
    const float* __restrict__ bq, const float* __restrict__ bk,
    const float* __restrict__ bv, const float* __restrict__ bs,
    float* __restrict__ biasf) {
  __shared__ float tt[32][33];
  int b = blockIdx.x, t = threadIdx.x;
  if (b < 2500) {
    int i = b * 256 + t;  // one per 4 elems, 640000 total
    float4 f = *(const float4*)&x[(size_t)i * 4];
    union { unsigned short u[4]; uint2 w; } o;
    o.u[0] = f2b(f.x); o.u[1] = f2b(f.y); o.u[2] = f2b(f.z); o.u[3] = f2b(f.w);
    *(uint2*)&xb[(size_t)i * 4] = o.w;
  } else if (b < 3268) {
    int zz = b - 2500;          // 768 tiles
    int z = zz >> 6, tile = zz & 63;
    int l = z >> 2, mat = z & 3;
    const float* W = (mat == 0 ? Wq : mat == 1 ? Wk : mat == 2 ? Wv : Ws)
                     + (size_t)l * C_DIM * C_DIM;
    int k0 = (tile >> 3) * 32, c0 = (tile & 7) * 32;
    int tx = t & 31, ty = t >> 5;
    for (int i = 0; i < 32; i += 8)
      tt[ty + i][tx] = W[(k0 + ty + i) * C_DIM + c0 + tx];
    __syncthreads();
    for (int i = 0; i < 32; i += 8) {
      int ncol = colmap(mat, c0 + ty + i);
      Wt[(size_t)l * GN * C_DIM + (size_t)ncol * C_DIM + k0 + tx] =
          __float2bfloat16(tt[tx][ty + i]);
    }
  } else {
    int i = (b - 3268) * 256 + t;
    if (i < L_LAYERS * GN) {
      int l = i >> 10, n = i & 1023;
      int mat = n >> 8, c = n & 255;
      const float* bb = (mat == 0 ? bq : mat == 1 ? bk : mat == 2 ? bv : bs);
      biasf[l * GN + colmap(mat, c)] = bb[l * C_DIM + c];
    }
  }
}

// ---------------- bf16 MFMA GEMM: [10000,256] @ Wt^T -> q|kv|skip ----------------
// 128x128 tile, BK=64, 256 threads (4 waves 2x2), LDS XOR-swizzled (T2 both-sides).
// kv blocks (col0 in [256,768)) stage the output tile in LDS (reusing As|Bs) and
// store interleaved k|v rows as coalesced uint4 into the [2][N][128] layout.
// q blocks store into [2][N][128] fp32 (slice = channel>>7).
__global__ __launch_bounds__(256) void gemm_kernel(
    const __hip_bfloat16* __restrict__ xb,   // [10000][256]
    const __hip_bfloat16* __restrict__ Wt,   // [1024][256] (this layer, col-paired)
    const float* __restrict__ biasf,         // [1024] (col-paired)
    float* __restrict__ q2,                  // [2][N][128] fp32
    unsigned short* __restrict__ kvu,        // [2][N][128] uint: k->lo, v->hi
    float* __restrict__ skip) {              // [N][256] fp32
  __shared__ __align__(16) unsigned short SH[16384];  // 32KB: As|Bs, reused for kv tile
  __hip_bfloat16* As = (__hip_bfloat16*)SH;
  __hip_bfloat16* Bs = (__hip_bfloat16*)(SH + 8192);
  int tid = threadIdx.x;
  int wid = tid >> 6, lane = tid & 63;
  int row0 = blockIdx.x * 128;
  int col0 = blockIdx.y * 128;
  int wr = wid >> 1, wc = wid & 1;
  int lr = lane & 15, lq = lane >> 4;
  int swz = (lr & 7) * 8;  // read-side XOR (elements)

  f32x4 acc[4][4] = {};

  for (int k0 = 0; k0 < C_DIM; k0 += 64) {
#pragma unroll
    for (int j = 0; j < 4; ++j) {
      int c = j * 256 + wid * 64 + lane;
      int arow = c >> 3;
      int kc = 8 * ((c & 7) ^ ((c >> 3) & 7));  // inverse-swizzled source
      int grow = row0 + arow;
      if (grow > N_NODES - 1) grow = N_NODES - 1;  // clamp: in-bounds, rows unused
      gload16(xb + (size_t)grow * C_DIM + k0 + kc, As + (size_t)(j * 256 + wid * 64) * 8);
    }
#pragma unroll
    for (int j = 0; j < 4; ++j) {
      int c = j * 256 + wid * 64 + lane;
      int brow = c >> 3;
      int kc = 8 * ((c & 7) ^ ((c >> 3) & 7));
      gload16(Wt + (size_t)(col0 + brow) * C_DIM + k0 + kc,
              Bs + (size_t)(j * 256 + wid * 64) * 8);
    }
    __syncthreads();

#pragma unroll
    for (int ks = 0; ks < 2; ++ks) {
      bf16x8 fa[4], fb[4];
#pragma unroll
      for (int m = 0; m < 4; ++m)
        fa[m] = *(const bf16x8*)&As[(wr * 64 + m * 16 + lr) * 64 + ((ks * 32 + lq * 8) ^ swz)];
#pragma unroll
      for (int n = 0; n < 4; ++n)
        fb[n] = *(const bf16x8*)&Bs[(wc * 64 + n * 16 + lr) * 64 + ((ks * 32 + lq * 8) ^ swz)];
#pragma unroll
      for (int m = 0; m < 4; ++m)
#pragma unroll
        for (int n = 0; n < 4; ++n)
          acc[m][n] = __builtin_amdgcn_mfma_f32_16x16x32_bf16(fa[m], fb[n], acc[m][n], 0, 0, 0);
    }
    __syncthreads();
  }

  float bias_n[4];
#pragma unroll
  for (int n = 0; n < 4; ++n) bias_n[n] = biasf[col0 + wc * 64 + n * 16 + lr];

  if (col0 >= 256 && col0 < 768) {
    // ---- kv path: stage interleaved k|v tile in LDS, then coalesced uint4 stores
    int half = wc;  // wc=0 -> k half, wc=1 -> v half (column pairing)
#pragma unroll
    for (int m = 0; m < 4; ++m) {
#pragma unroll
      for (int n = 0; n < 4; ++n) {
        int chs = n * 16 + lr;  // channel-in-64-block 0..63
#pragma unroll
        for (int r = 0; r < 4; ++r) {
          int row = wr * 64 + m * 16 + lq * 4 + r;
          SH[row * 128 + chs * 2 + half] = f2b(acc[m][n][r] + bias_n[n]);
        }
      }
    }
    __syncthreads();
    int bl = (col0 - 256) >> 7;       // 64-ch block 0..3
    int sl = bl >> 1;                 // slice 0..1
    int h64 = (bl & 1) * 64;          // 64-ch half within 128-ch slice
    unsigned int* kvd = (unsigned int*)kvu;
    int t16 = tid & 15, rbase = tid >> 4;
#pragma unroll
    for (int it = 0; it < 8; ++it) {
      int row = it * 16 + rbase;
      int grow = row0 + row;
      if (grow < N_NODES) {
        uint4 vv = *(const uint4*)&SH[row * 128 + t16 * 8];  // channels [4*t16,4*t16+4)
        *(uint4*)&kvd[((size_t)sl * N_NODES + grow) * 128 + h64 + t16 * 4] = vv;
      }
    }
  } else {
    // ---- q / skip scalar path
#pragma unroll
    for (int m = 0; m < 4; ++m) {
#pragma unroll
      for (int n = 0; n < 4; ++n) {
        int colG = col0 + wc * 64 + n * 16 + lr;
#pragma unroll
        for (int r = 0; r < 4; ++r) {
          int grow = row0 + wr * 64 + m * 16 + lq * 4 + r;
          if (grow < N_NODES) {
            float val = acc[m][n][r] + bias_n[n];
            if (col0 < 256) {
              q2[((size_t)(colG >> 7) * N_NODES + grow) * 128 + (colG & 127)] = val;
            } else {
              skip[(size_t)grow * C_DIM + (colG - 768)] = val;
            }
          }
        }
      }
    }
  }
}

// ---------------- per-node aggregation, no-max softmax (2x128ch slices) ----------------
// Wave = (4 contiguous nodes, 128-ch slice); slot = lane>>5 (2 edges in parallel);
// 4 ch/lane; head = 8-lane group. slice = blockIdx&1 -> XCD parity pinning.
// Batched prologue: all 5 row_ptr, 4 q-vectors, and 4 first-index pairs issued
// upfront as independent loads (one latency instead of 4x3 dependent chains).
// srcs are pre-scaled byte offsets (src*512) -> gather addr is base+offset.
// Scores |s| << 87 -> no-max softmax exact; q pre-scaled by log2e/sqrt(32).
// Depth-2 pipeline per node: t+1 kv gathers + t+2 indices in flight; 2-wide tail.
__global__ __launch_bounds__(256) void agg_kernel(
    const float* __restrict__ q2,          // [2][N][128] fp32
    const unsigned int* __restrict__ kv2,  // [2][N][128] k|v bf16 pairs
    const int* __restrict__ row_ptr, const int* __restrict__ srcs,
    float* __restrict__ out, __hip_bfloat16* __restrict__ xb_next) {
  int b = blockIdx.x;
  int slice = b & 1;
  int wid = threadIdx.x >> 6, lane = threadIdx.x & 63;
  int n0 = (b >> 1) * 16 + wid * 4;         // 4 nodes per wave
  int slot = lane >> 5;                     // 2 edge-slots per wave
  int l4 = (lane & 31) * 4;                 // 4 ch/lane, 128 ch per slice
  const size_t SB = (size_t)slice * N_NODES * 128;
  const float scl = 0.25503526f;            // log2(e)/sqrt(32)
  const char* kvb = (const char*)(kv2 + SB) + l4 * 4;  // per-lane gather base

  // ---- batched prologue: independent loads for all 4 nodes
  int rp[5];
#pragma unroll
  for (int m = 0; m < 5; ++m) rp[m] = row_ptr[n0 + m];

  float4 qv[4];
#pragma unroll
  for (int m = 0; m < 4; ++m) {
    qv[m] = *(const float4*)&q2[SB + (size_t)(n0 + m) * 128 + l4];
    qv[m].x *= scl; qv[m].y *= scl; qv[m].z *= scl; qv[m].w *= scl;
  }

  int f0[4], f1[4];                         // first index pair per node
#pragma unroll
  for (int m = 0; m < 4; ++m) {
    int beg = rp[m], end = rp[m + 1];
    int ja = beg + slot;     if (ja >= end) ja = beg;
    int jb = beg + 2 + slot; if (jb >= end) jb = beg;
    if (ja >= E_EDGES) ja = 0;
    if (jb >= E_EDGES) jb = 0;
    f0[m] = srcs[ja];
    f1[m] = srcs[jb];
  }

#pragma unroll
  for (int m = 0; m < 4; ++m) {
    int beg = rp[m], end = rp[m + 1];
    float l = 0.f;
    float4 a = make_float4(0.f, 0.f, 0.f, 0.f);

    int i = beg;
    int sa1 = 0, sb1 = 0;
    uint4 wa = make_uint4(0, 0, 0, 0), wb = make_uint4(0, 0, 0, 0);
    if (i + 4 <= end) {                     // first gathers (indices pre-resident)
      wa = *(const uint4*)(kvb + f0[m]);
      wb = *(const uint4*)(kvb + f1[m]);
      if (i + 8 <= end) { sa1 = srcs[i + 4 + slot]; sb1 = srcs[i + 6 + slot]; }
    }
    while (i + 4 <= end) {
      uint4 na = make_uint4(0, 0, 0, 0), nb = make_uint4(0, 0, 0, 0);
      if (i + 8 <= end) {                   // issue t+1 kv (indices already resident)
        na = *(const uint4*)(kvb + sa1);
        nb = *(const uint4*)(kvb + sb1);
        if (i + 12 <= end) {                // issue t+2 indices
          sa1 = srcs[i + 8 + slot]; sb1 = srcs[i + 10 + slot];
        }
      }
      float pa = red8(dot4(qv[m], wa));
      float pb = red8(dot4(qv[m], wb));
      float ea = exp2f(pa), eb = exp2f(pb);
      l += ea + eb;
      a.x = fmaf(ea, kv_hi(wa.x), fmaf(eb, kv_hi(wb.x), a.x));
      a.y = fmaf(ea, kv_hi(wa.y), fmaf(eb, kv_hi(wb.y), a.y));
      a.z = fmaf(ea, kv_hi(wa.z), fmaf(eb, kv_hi(wb.z), a.z));
      a.w = fmaf(ea, kv_hi(wa.w), fmaf(eb, kv_hi(wb.w), a.w));
      wa = na; wb = nb;
      i += 4;
    }
    for (; i < end; i += 2) {               // guarded 2-wide tail (<= 2 iters)
      int j = i + slot;
      bool valid = j < end;
      int s = srcs[valid ? j : beg];
      uint4 w = *(const uint4*)(kvb + s);
      float p = red8(dot4(qv[m], w));
      float e = valid ? exp2f(p) : 0.f;
      l += e;
      a.x = fmaf(e, kv_hi(w.x), a.x);
      a.y = fmaf(e, kv_hi(w.y), a.y);
      a.z = fmaf(e, kv_hi(w.z), a.z);
      a.w = fmaf(e, kv_hi(w.w), a.w);
    }

    // merge the 2 edge-slots (pure adds; both halves get totals)
    l   += __shfl_xor(l, 32);
    a.x += __shfl_xor(a.x, 32);
    a.y += __shfl_xor(a.y, 32);
    a.z += __shfl_xor(a.z, 32);
    a.w += __shfl_xor(a.w, 32);

    if (lane < 32) {
      float inv = 1.f / (l + 1e-16f);
      size_t idx = (size_t)(n0 + m) * C_DIM + slice * 128 + l4;
      float4 o = *(const float4*)&out[idx];
      o.x += a.x * inv; o.y += a.y * inv; o.z += a.z * inv; o.w += a.w * inv;
      *(float4*)&out[idx] = o;
      union { unsigned short us[4]; uint2 w; } ob;
      ob.us[0] = f2b(o.x); ob.us[1] = f2b(o.y); ob.us[2] = f2b(o.z); ob.us[3] = f2b(o.w);
      *(uint2*)&xb_next[idx] = ob.w;
    }
  }
}

extern "C" void kernel_launch(void* const* d_in, const int* in_sizes, int n_in,
                              void* d_out, int out_size, void* d_ws, size_t ws_size,
                              hipStream_t stream) {
  const float* x0 = (const float*)d_in[0];
  const float* Wq = (const float*)d_in[1];
  const float* bq = (const float*)d_in[2];
  const float* Wk = (const float*)d_in[3];
  const float* bk = (const float*)d_in[4];
  const float* Wv = (const float*)d_in[5];
  const float* bv = (const float*)d_in[6];
  const float* Ws = (const float*)d_in[7];
  const float* bs = (const float*)d_in[8];
  const int* ei  = (const int*)d_in[9];
  const int* src = ei;
  const int* dst = ei + E_EDGES;
  float* out = (float*)d_out;

  const size_t NC = (size_t)N_NODES * C_DIM;  // 2,560,000
  __hip_bfloat16* xb = (__hip_bfloat16*)d_ws;
  unsigned int* kvbuf = (unsigned int*)(xb + NC);       // [2][N][128] k|v bf16 pairs
  __hip_bfloat16* Wt = (__hip_bfloat16*)(kvbuf + NC);   // 3*1024*256
  float* qbuf  = (float*)(Wt + (size_t)L_LAYERS * GN * C_DIM);  // [2][N][128]
  float* skipA = qbuf + NC;
  float* biasf = skipA + NC;                            // 3*1024
  int* row_ptr = (int*)(biasf + L_LAYERS * GN);
  int* deg  = row_ptr + (N_NODES + 1);
  int* fill = deg + N_NODES;
  int* srcs = fill + N_NODES;

  (void)hipMemsetAsync(deg, 0, 2 * N_NODES * sizeof(int), stream);  // deg + fill
  hist_kernel<<<(E_EDGES + 255) / 256, 256, 0, stream>>>(dst, deg);
  scan_kernel<<<1, 1024, 0, stream>>>(deg, row_ptr);
  scatter_kernel<<<(E_EDGES + 255) / 256, 256, 0, stream>>>(src, dst, row_ptr, fill, srcs);

  conv_all_kernel<<<3281, 256, 0, stream>>>(x0, xb, Wq, Wk, Wv, Ws, Wt,
                                            bq, bk, bv, bs, biasf);

  for (int l = 0; l < L_LAYERS; ++l) {
    float* skip = (l == L_LAYERS - 1) ? out : skipA;
    gemm_kernel<<<dim3((N_NODES + 127) / 128, GN / 128), 256, 0, stream>>>(
        xb, Wt + (size_t)l * GN * C_DIM, biasf + l * GN, qbuf,
        (unsigned short*)kvbuf, skip);
    agg_kernel<<<dim3(2 * (N_NODES / 16)), 256, 0, stream>>>(
        qbuf, kvbuf, row_ptr, srcs, skip, xb);
  }
}

// Round 10
// 210.380 us; speedup vs baseline: 1.1087x; 1.0624x over previous
//
#include <hip/hip_runtime.h>
#include <hip/hip_bf16.h>

#define N_NODES 10000
#define C_DIM   256
#define H_HEADS 8
#define D_HEAD  32
#define E_EDGES 320000
#define L_LAYERS 3
#define GN      1024   // fused q|kv-paired|skip output width

typedef __attribute__((ext_vector_type(8))) short bf16x8;
typedef __attribute__((ext_vector_type(4))) float f32x4;

__device__ __forceinline__ unsigned short f2b(float f) {
  __hip_bfloat16 h = __float2bfloat16(f);
  return *(unsigned short*)&h;
}

__device__ __forceinline__ float kv_lo(unsigned int w) {  // k in low ushort
  union { unsigned int u; float f; } c; c.u = w << 16; return c.f;
}
__device__ __forceinline__ float kv_hi(unsigned int w) {  // v in high ushort
  union { unsigned int u; float f; } c; c.u = w & 0xffff0000u; return c.f;
}

__device__ __forceinline__ float red8(float p) {  // sum over 8-lane group (one head)
  p += __shfl_xor(p, 1);
  p += __shfl_xor(p, 2);
  p += __shfl_xor(p, 4);
  return p;
}

__device__ __forceinline__ float dot4(float4 q, uint4 w) {
  return fmaf(q.x, kv_lo(w.x),
         fmaf(q.y, kv_lo(w.y),
         fmaf(q.z, kv_lo(w.z), q.w * kv_lo(w.w))));
}

__device__ __forceinline__ void gload16(const void* g, void* l) {
  __builtin_amdgcn_global_load_lds(
      (const __attribute__((address_space(1))) unsigned int*)g,
      (__attribute__((address_space(3))) unsigned int*)l, 16, 0, 0);
}

// fused-column map: q -> c, k -> 256+(c>>6)*128+(c&63), v -> +64, s -> 768+c
__device__ __forceinline__ int colmap(int mat, int c) {
  if (mat == 0) return c;
  if (mat == 3) return 768 + c;
  return 256 + ((c >> 6) << 7) + ((mat - 1) << 6) + (c & 63);
}

// ---------------- CSR build (dst -> list of src) ----------------
__global__ void hist_kernel(const int* __restrict__ dst, int* __restrict__ deg) {
  int e = blockIdx.x * blockDim.x + threadIdx.x;
  if (e < E_EDGES) atomicAdd(&deg[dst[e]], 1);
}

__global__ __launch_bounds__(1024) void scan_kernel(const int* __restrict__ deg,
                                                    int* __restrict__ row_ptr) {
  __shared__ int part[1024];
  int t = threadIdx.x;
  const int CHUNK = (N_NODES + 1023) / 1024;  // 10
  int base = t * CHUNK;
  int s = 0;
  for (int i = 0; i < CHUNK; ++i) {
    int idx = base + i;
    if (idx < N_NODES) s += deg[idx];
  }
  part[t] = s;
  __syncthreads();
  for (int off = 1; off < 1024; off <<= 1) {
    int v = (t >= off) ? part[t - off] : 0;
    __syncthreads();
    part[t] += v;
    __syncthreads();
  }
  int run = (t == 0) ? 0 : part[t - 1];
  for (int i = 0; i < CHUNK; ++i) {
    int idx = base + i;
    if (idx <= N_NODES) {
      row_ptr[idx] = run;
      if (idx < N_NODES) run += deg[idx];
    }
  }
}

// srcs stores BYTE OFFSETS into a kv slice (src*512 = src*128ch*4B) so the agg
// gather address is a plain base+offset (no per-edge shift/mul chain).
__global__ void scatter_kernel(const int* __restrict__ src, const int* __restrict__ dst,
                               const int* __restrict__ row_ptr, int* __restrict__ fill,
                               int* __restrict__ srcs) {
  int e = blockIdx.x * blockDim.x + threadIdx.x;
  if (e < E_EDGES) {
    int d = dst[e];
    int pos = atomicAdd(&fill[d], 1);
    srcs[row_ptr[d] + pos] = src[e] << 9;
  }
}

// ---------------- fused one-time converts (x, W, b) ----------------
// blocks [0,2500): convx; [2500,3268): convw tiles; [3268,3281): convb
__global__ __launch_bounds__(256) void conv_all_kernel(
    const float* __restrict__ x, __hip_bfloat16* __restrict__ xb,
    const float* __restrict__ Wq, const float* __restrict__ Wk,
    const float* __restrict__ Wv, const float* __restrict__ Ws,
    __hip_bfloat16* __restrict__ Wt,
    const float* __restrict__ bq, const float* __restrict__ bk,
    const float* __restrict__ bv, const float* __restrict__ bs,
    float* __restrict__ biasf) {
  __shared__ float tt[32][33];
  int b = blockIdx.x, t = threadIdx.x;
  if (b < 2500) {
    int i = b * 256 + t;  // one per 4 elems, 640000 total
    float4 f = *(const float4*)&x[(size_t)i * 4];
    union { unsigned short u[4]; uint2 w; } o;
    o.u[0] = f2b(f.x); o.u[1] = f2b(f.y); o.u[2] = f2b(f.z); o.u[3] = f2b(f.w);
    *(uint2*)&xb[(size_t)i * 4] = o.w;
  } else if (b < 3268) {
    int zz = b - 2500;          // 768 tiles
    int z = zz >> 6, tile = zz & 63;
    int l = z >> 2, mat = z & 3;
    const float* W = (mat == 0 ? Wq : mat == 1 ? Wk : mat == 2 ? Wv : Ws)
                     + (size_t)l * C_DIM * C_DIM;
    int k0 = (tile >> 3) * 32, c0 = (tile & 7) * 32;
    int tx = t & 31, ty = t >> 5;
    for (int i = 0; i < 32; i += 8)
      tt[ty + i][tx] = W[(k0 + ty + i) * C_DIM + c0 + tx];
    __syncthreads();
    for (int i = 0; i < 32; i += 8) {
      int ncol = colmap(mat, c0 + ty + i);
      Wt[(size_t)l * GN * C_DIM + (size_t)ncol * C_DIM + k0 + tx] =
          __float2bfloat16(tt[tx][ty + i]);
    }
  } else {
    int i = (b - 3268) * 256 + t;
    if (i < L_LAYERS * GN) {
      int l = i >> 10, n = i & 1023;
      int mat = n >> 8, c = n & 255;
      const float* bb = (mat == 0 ? bq : mat == 1 ? bk : mat == 2 ? bv : bs);
      biasf[l * GN + colmap(mat, c)] = bb[l * C_DIM + c];
    }
  }
}

// ---------------- bf16 MFMA GEMM: [10000,256] @ Wt^T -> q|kv|skip ----------------
// 128x128 tile, BK=64, 256 threads (4 waves 2x2), LDS XOR-swizzled (T2 both-sides).
// kv blocks (col0 in [256,768)) stage the output tile in LDS (reusing As|Bs) and
// store interleaved k|v rows as coalesced uint4 into the [2][N][128] layout.
// q blocks store into [2][N][128] fp32 (slice = channel>>7).
__global__ __launch_bounds__(256) void gemm_kernel(
    const __hip_bfloat16* __restrict__ xb,   // [10000][256]
    const __hip_bfloat16* __restrict__ Wt,   // [1024][256] (this layer, col-paired)
    const float* __restrict__ biasf,         // [1024] (col-paired)
    float* __restrict__ q2,                  // [2][N][128] fp32
    unsigned short* __restrict__ kvu,        // [2][N][128] uint: k->lo, v->hi
    float* __restrict__ skip) {              // [N][256] fp32
  __shared__ __align__(16) unsigned short SH[16384];  // 32KB: As|Bs, reused for kv tile
  __hip_bfloat16* As = (__hip_bfloat16*)SH;
  __hip_bfloat16* Bs = (__hip_bfloat16*)(SH + 8192);
  int tid = threadIdx.x;
  int wid = tid >> 6, lane = tid & 63;
  int row0 = blockIdx.x * 128;
  int col0 = blockIdx.y * 128;
  int wr = wid >> 1, wc = wid & 1;
  int lr = lane & 15, lq = lane >> 4;
  int swz = (lr & 7) * 8;  // read-side XOR (elements)

  f32x4 acc[4][4] = {};

  for (int k0 = 0; k0 < C_DIM; k0 += 64) {
#pragma unroll
    for (int j = 0; j < 4; ++j) {
      int c = j * 256 + wid * 64 + lane;
      int arow = c >> 3;
      int kc = 8 * ((c & 7) ^ ((c >> 3) & 7));  // inverse-swizzled source
      int grow = row0 + arow;
      if (grow > N_NODES - 1) grow = N_NODES - 1;  // clamp: in-bounds, rows unused
      gload16(xb + (size_t)grow * C_DIM + k0 + kc, As + (size_t)(j * 256 + wid * 64) * 8);
    }
#pragma unroll
    for (int j = 0; j < 4; ++j) {
      int c = j * 256 + wid * 64 + lane;
      int brow = c >> 3;
      int kc = 8 * ((c & 7) ^ ((c >> 3) & 7));
      gload16(Wt + (size_t)(col0 + brow) * C_DIM + k0 + kc,
              Bs + (size_t)(j * 256 + wid * 64) * 8);
    }
    __syncthreads();

#pragma unroll
    for (int ks = 0; ks < 2; ++ks) {
      bf16x8 fa[4], fb[4];
#pragma unroll
      for (int m = 0; m < 4; ++m)
        fa[m] = *(const bf16x8*)&As[(wr * 64 + m * 16 + lr) * 64 + ((ks * 32 + lq * 8) ^ swz)];
#pragma unroll
      for (int n = 0; n < 4; ++n)
        fb[n] = *(const bf16x8*)&Bs[(wc * 64 + n * 16 + lr) * 64 + ((ks * 32 + lq * 8) ^ swz)];
#pragma unroll
      for (int m = 0; m < 4; ++m)
#pragma unroll
        for (int n = 0; n < 4; ++n)
          acc[m][n] = __builtin_amdgcn_mfma_f32_16x16x32_bf16(fa[m], fb[n], acc[m][n], 0, 0, 0);
    }
    __syncthreads();
  }

  float bias_n[4];
#pragma unroll
  for (int n = 0; n < 4; ++n) bias_n[n] = biasf[col0 + wc * 64 + n * 16 + lr];

  if (col0 >= 256 && col0 < 768) {
    // ---- kv path: stage interleaved k|v tile in LDS, then coalesced uint4 stores
    int half = wc;  // wc=0 -> k half, wc=1 -> v half (column pairing)
#pragma unroll
    for (int m = 0; m < 4; ++m) {
#pragma unroll
      for (int n = 0; n < 4; ++n) {
        int chs = n * 16 + lr;  // channel-in-64-block 0..63
#pragma unroll
        for (int r = 0; r < 4; ++r) {
          int row = wr * 64 + m * 16 + lq * 4 + r;
          SH[row * 128 + chs * 2 + half] = f2b(acc[m][n][r] + bias_n[n]);
        }
      }
    }
    __syncthreads();
    int bl = (col0 - 256) >> 7;       // 64-ch block 0..3
    int sl = bl >> 1;                 // slice 0..1
    int h64 = (bl & 1) * 64;          // 64-ch half within 128-ch slice
    unsigned int* kvd = (unsigned int*)kvu;
    int t16 = tid & 15, rbase = tid >> 4;
#pragma unroll
    for (int it = 0; it < 8; ++it) {
      int row = it * 16 + rbase;
      int grow = row0 + row;
      if (grow < N_NODES) {
        uint4 vv = *(const uint4*)&SH[row * 128 + t16 * 8];  // channels [4*t16,4*t16+4)
        *(uint4*)&kvd[((size_t)sl * N_NODES + grow) * 128 + h64 + t16 * 4] = vv;
      }
    }
  } else {
    // ---- q / skip scalar path
#pragma unroll
    for (int m = 0; m < 4; ++m) {
#pragma unroll
      for (int n = 0; n < 4; ++n) {
        int colG = col0 + wc * 64 + n * 16 + lr;
#pragma unroll
        for (int r = 0; r < 4; ++r) {
          int grow = row0 + wr * 64 + m * 16 + lq * 4 + r;
          if (grow < N_NODES) {
            float val = acc[m][n][r] + bias_n[n];
            if (col0 < 256) {
              q2[((size_t)(colG >> 7) * N_NODES + grow) * 128 + (colG & 127)] = val;
            } else {
              skip[(size_t)grow * C_DIM + (colG - 768)] = val;
            }
          }
        }
      }
    }
  }
}

// ---------------- per-node aggregation, no-max softmax (2x128ch slices) ----------------
// Wave = (node, 128-ch slice); slot = lane>>5 (2 edges in parallel); 4 ch/lane;
// head = 8-lane group (4 heads per slice). slice = blockIdx&1 -> XCD parity
// pinning. srcs are pre-scaled byte offsets (src*512): gather addr = base+offset.
// Scores |s| << 87 -> softmax without max subtraction exact (shift-invariance);
// q pre-scaled by log2e/sqrt(32), e = exp2(p).
// Depth-2 pipeline: 4 edges/iter, t+1 kv and t+2 indices in flight; 2-wide tail.
__global__ __launch_bounds__(256) void agg_kernel(
    const float* __restrict__ q2,          // [2][N][128] fp32
    const unsigned int* __restrict__ kv2,  // [2][N][128] k|v bf16 pairs
    const int* __restrict__ row_ptr, const int* __restrict__ srcs,
    float* __restrict__ out, __hip_bfloat16* __restrict__ xb_next) {
  int b = blockIdx.x;
  int slice = b & 1;
  int wid = threadIdx.x >> 6, lane = threadIdx.x & 63;
  int n = (b >> 1) * 4 + wid;
  int slot = lane >> 5;                     // 2 edge-slots per wave
  int l4 = (lane & 31) * 4;                 // 4 ch/lane, 128 ch per slice
  const size_t SB = (size_t)slice * N_NODES * 128;
  const float scl = 0.25503526f;            // log2(e)/sqrt(32)
  const char* kvb = (const char*)(kv2 + SB) + l4 * 4;  // per-lane gather base

  float4 qv = *(const float4*)&q2[SB + (size_t)n * 128 + l4];
  qv.x *= scl; qv.y *= scl; qv.z *= scl; qv.w *= scl;

  int beg = row_ptr[n], end = row_ptr[n + 1];
  float l = 0.f;
  float4 a = make_float4(0.f, 0.f, 0.f, 0.f);

  int i = beg;
  int sa1 = 0, sb1 = 0;
  uint4 wa = make_uint4(0, 0, 0, 0), wb = make_uint4(0, 0, 0, 0);
  if (i + 4 <= end) {                       // prologue: iter0 kv + iter1 indices
    int sa0 = srcs[i + slot], sb0 = srcs[i + 2 + slot];
    wa = *(const uint4*)(kvb + sa0);
    wb = *(const uint4*)(kvb + sb0);
    if (i + 8 <= end) { sa1 = srcs[i + 4 + slot]; sb1 = srcs[i + 6 + slot]; }
  }
  while (i + 4 <= end) {
    uint4 na = make_uint4(0, 0, 0, 0), nb = make_uint4(0, 0, 0, 0);
    if (i + 8 <= end) {                     // issue t+1 kv (indices already resident)
      na = *(const uint4*)(kvb + sa1);
      nb = *(const uint4*)(kvb + sb1);
      if (i + 12 <= end) {                  // issue t+2 indices
        sa1 = srcs[i + 8 + slot]; sb1 = srcs[i + 10 + slot];
      }
    }
    float pa = red8(dot4(qv, wa));
    float pb = red8(dot4(qv, wb));
    float ea = exp2f(pa), eb = exp2f(pb);
    l += ea + eb;
    a.x = fmaf(ea, kv_hi(wa.x), fmaf(eb, kv_hi(wb.x), a.x));
    a.y = fmaf(ea, kv_hi(wa.y), fmaf(eb, kv_hi(wb.y), a.y));
    a.z = fmaf(ea, kv_hi(wa.z), fmaf(eb, kv_hi(wb.z), a.z));
    a.w = fmaf(ea, kv_hi(wa.w), fmaf(eb, kv_hi(wb.w), a.w));
    wa = na; wb = nb;
    i += 4;
  }
  for (; i < end; i += 2) {                 // guarded 2-wide tail (<= 2 iters)
    int j = i + slot;
    bool valid = j < end;
    int s = srcs[valid ? j : beg];
    uint4 w = *(const uint4*)(kvb + s);
    float p = red8(dot4(qv, w));
    float e = valid ? exp2f(p) : 0.f;
    l += e;
    a.x = fmaf(e, kv_hi(w.x), a.x);
    a.y = fmaf(e, kv_hi(w.y), a.y);
    a.z = fmaf(e, kv_hi(w.z), a.z);
    a.w = fmaf(e, kv_hi(w.w), a.w);
  }

  // merge the 2 edge-slots (pure adds; both halves get totals)
  l   += __shfl_xor(l, 32);
  a.x += __shfl_xor(a.x, 32);
  a.y += __shfl_xor(a.y, 32);
  a.z += __shfl_xor(a.z, 32);
  a.w += __shfl_xor(a.w, 32);

  if (lane < 32) {
    float inv = 1.f / (l + 1e-16f);
    size_t idx = (size_t)n * C_DIM + slice * 128 + l4;
    float4 o = *(const float4*)&out[idx];
    o.x += a.x * inv; o.y += a.y * inv; o.z += a.z * inv; o.w += a.w * inv;
    *(float4*)&out[idx] = o;
    union { unsigned short us[4]; uint2 w; } ob;
    ob.us[0] = f2b(o.x); ob.us[1] = f2b(o.y); ob.us[2] = f2b(o.z); ob.us[3] = f2b(o.w);
    *(uint2*)&xb_next[idx] = ob.w;
  }
}

extern "C" void kernel_launch(void* const* d_in, const int* in_sizes, int n_in,
                              void* d_out, int out_size, void* d_ws, size_t ws_size,
                              hipStream_t stream) {
  const float* x0 = (const float*)d_in[0];
  const float* Wq = (const float*)d_in[1];
  const float* bq = (const float*)d_in[2];
  const float* Wk = (const float*)d_in[3];
  const float* bk = (const float*)d_in[4];
  const float* Wv = (const float*)d_in[5];
  const float* bv = (const float*)d_in[6];
  const float* Ws = (const float*)d_in[7];
  const float* bs = (const float*)d_in[8];
  const int* ei  = (const int*)d_in[9];
  const int* src = ei;
  const int* dst = ei + E_EDGES;
  float* out = (float*)d_out;

  const size_t NC = (size_t)N_NODES * C_DIM;  // 2,560,000
  __hip_bfloat16* xb = (__hip_bfloat16*)d_ws;
  unsigned int* kvbuf = (unsigned int*)(xb + NC);       // [2][N][128] k|v bf16 pairs
  __hip_bfloat16* Wt = (__hip_bfloat16*)(kvbuf + NC);   // 3*1024*256
  float* qbuf  = (float*)(Wt + (size_t)L_LAYERS * GN * C_DIM);  // [2][N][128]
  float* skipA = qbuf + NC;
  float* biasf = skipA + NC;                            // 3*1024
  int* row_ptr = (int*)(biasf + L_LAYERS * GN);
  int* deg  = row_ptr + (N_NODES + 1);
  int* fill = deg + N_NODES;
  int* srcs = fill + N_NODES;

  (void)hipMemsetAsync(deg, 0, 2 * N_NODES * sizeof(int), stream);  // deg + fill
  hist_kernel<<<(E_EDGES + 255) / 256, 256, 0, stream>>>(dst, deg);
  scan_kernel<<<1, 1024, 0, stream>>>(deg, row_ptr);
  scatter_kernel<<<(E_EDGES + 255) / 256, 256, 0, stream>>>(src, dst, row_ptr, fill, srcs);

  conv_all_kernel<<<3281, 256, 0, stream>>>(x0, xb, Wq, Wk, Wv, Ws, Wt,
                                            bq, bk, bv, bs, biasf);

  for (int l = 0; l < L_LAYERS; ++l) {
    float* skip = (l == L_LAYERS - 1) ? out : skipA;
    gemm_kernel<<<dim3((N_NODES + 127) / 128, GN / 128), 256, 0, stream>>>(
        xb, Wt + (size_t)l * GN * C_DIM, biasf + l * GN, qbuf,
        (unsigned short*)kvbuf, skip);
    agg_kernel<<<dim3(2 * (N_NODES / 4)), 256, 0, stream>>>(
        qbuf, kvbuf, row_ptr, srcs, skip, xb);
  }
}

// Round 11
// 200.355 us; speedup vs baseline: 1.1641x; 1.0500x over previous
//
#include <hip/hip_runtime.h>
#include <hip/hip_bf16.h>

#define N_NODES 10000
#define C_DIM   256
#define H_HEADS 8
#define D_HEAD  32
#define E_EDGES 320000
#define L_LAYERS 3
#define GN      1024   // fused q|kv-paired|skip output width

typedef __attribute__((ext_vector_type(8))) short bf16x8;
typedef __attribute__((ext_vector_type(4))) float f32x4;

__device__ __forceinline__ unsigned short f2b(float f) {
  __hip_bfloat16 h = __float2bfloat16(f);
  return *(unsigned short*)&h;
}

__device__ __forceinline__ float kv_lo(unsigned int w) {  // k in low ushort
  union { unsigned int u; float f; } c; c.u = w << 16; return c.f;
}
__device__ __forceinline__ float kv_hi(unsigned int w) {  // v in high ushort
  union { unsigned int u; float f; } c; c.u = w & 0xffff0000u; return c.f;
}

__device__ __forceinline__ float red8(float p) {  // sum over 8-lane group (one head)
  p += __shfl_xor(p, 1);
  p += __shfl_xor(p, 2);
  p += __shfl_xor(p, 4);
  return p;
}

__device__ __forceinline__ float dot4(float4 q, uint4 w) {
  return fmaf(q.x, kv_lo(w.x),
         fmaf(q.y, kv_lo(w.y),
         fmaf(q.z, kv_lo(w.z), q.w * kv_lo(w.w))));
}

__device__ __forceinline__ void gload16(const void* g, void* l) {
  __builtin_amdgcn_global_load_lds(
      (const __attribute__((address_space(1))) unsigned int*)g,
      (__attribute__((address_space(3))) unsigned int*)l, 16, 0, 0);
}

// fused-column map: q -> c, k -> 256+(c>>6)*128+(c&63), v -> +64, s -> 768+c
__device__ __forceinline__ int colmap(int mat, int c) {
  if (mat == 0) return c;
  if (mat == 3) return 768 + c;
  return 256 + ((c >> 6) << 7) + ((mat - 1) << 6) + (c & 63);
}

// ---------------- CSR build (dst -> list of src) ----------------
__global__ void hist_kernel(const int* __restrict__ dst, int* __restrict__ deg) {
  int e = blockIdx.x * blockDim.x + threadIdx.x;
  if (e < E_EDGES) atomicAdd(&deg[dst[e]], 1);
}

__global__ __launch_bounds__(1024) void scan_kernel(const int* __restrict__ deg,
                                                    int* __restrict__ row_ptr) {
  __shared__ int part[1024];
  int t = threadIdx.x;
  const int CHUNK = (N_NODES + 1023) / 1024;  // 10
  int base = t * CHUNK;
  int s = 0;
  for (int i = 0; i < CHUNK; ++i) {
    int idx = base + i;
    if (idx < N_NODES) s += deg[idx];
  }
  part[t] = s;
  __syncthreads();
  for (int off = 1; off < 1024; off <<= 1) {
    int v = (t >= off) ? part[t - off] : 0;
    __syncthreads();
    part[t] += v;
    __syncthreads();
  }
  int run = (t == 0) ? 0 : part[t - 1];
  for (int i = 0; i < CHUNK; ++i) {
    int idx = base + i;
    if (idx <= N_NODES) {
      row_ptr[idx] = run;
      if (idx < N_NODES) run += deg[idx];
    }
  }
}

__global__ void scatter_kernel(const int* __restrict__ src, const int* __restrict__ dst,
                               const int* __restrict__ row_ptr, int* __restrict__ fill,
                               int* __restrict__ srcs) {
  int e = blockIdx.x * blockDim.x + threadIdx.x;
  if (e < E_EDGES) {
    int d = dst[e];
    int pos = atomicAdd(&fill[d], 1);
    srcs[row_ptr[d] + pos] = src[e];
  }
}

// ---------------- fused one-time converts (x, W, b) ----------------
// blocks [0,2500): convx; [2500,3268): convw tiles; [3268,3281): convb
__global__ __launch_bounds__(256) void conv_all_kernel(
    const float* __restrict__ x, __hip_bfloat16* __restrict__ xb,
    const float* __restrict__ Wq, const float* __restrict__ Wk,
    const float* __restrict__ Wv, const float* __restrict__ Ws,
    __hip_bfloat16* __restrict__ Wt,
    const float* __restrict__ bq, const float* __restrict__ bk,
    const float* __restrict__ bv, const float* __restrict__ bs,
    float* __restrict__ biasf) {
  __shared__ float tt[32][33];
  int b = blockIdx.x, t = threadIdx.x;
  if (b < 2500) {
    int i = b * 256 + t;  // one per 4 elems, 640000 total
    float4 f = *(const float4*)&x[(size_t)i * 4];
    union { unsigned short u[4]; uint2 w; } o;
    o.u[0] = f2b(f.x); o.u[1] = f2b(f.y); o.u[2] = f2b(f.z); o.u[3] = f2b(f.w);
    *(uint2*)&xb[(size_t)i * 4] = o.w;
  } else if (b < 3268) {
    int zz = b - 2500;          // 768 tiles
    int z = zz >> 6, tile = zz & 63;
    int l = z >> 2, mat = z & 3;
    const float* W = (mat == 0 ? Wq : mat == 1 ? Wk : mat == 2 ? Wv : Ws)
                     + (size_t)l * C_DIM * C_DIM;
    int k0 = (tile >> 3) * 32, c0 = (tile & 7) * 32;
    int tx = t & 31, ty = t >> 5;
    for (int i = 0; i < 32; i += 8)
      tt[ty + i][tx] = W[(k0 + ty + i) * C_DIM + c0 + tx];
    __syncthreads();
    for (int i = 0; i < 32; i += 8) {
      int ncol = colmap(mat, c0 + ty + i);
      Wt[(size_t)l * GN * C_DIM + (size_t)ncol * C_DIM + k0 + tx] =
          __float2bfloat16(tt[tx][ty + i]);
    }
  } else {
    int i = (b - 3268) * 256 + t;
    if (i < L_LAYERS * GN) {
      int l = i >> 10, n = i & 1023;
      int mat = n >> 8, c = n & 255;
      const float* bb = (mat == 0 ? bq : mat == 1 ? bk : mat == 2 ? bv : bs);
      biasf[l * GN + colmap(mat, c)] = bb[l * C_DIM + c];
    }
  }
}

// ---------------- bf16 MFMA GEMM: [10000,256] @ Wt^T -> q|kv|skip ----------------
// 128x128 tile, BK=64, 256 threads (4 waves 2x2), LDS XOR-swizzled (T2 both-sides).
// kv blocks (col0 in [256,768)) stage the output tile in LDS (reusing As|Bs) and
// store interleaved k|v rows as coalesced uint4 into the [2][N][128] layout.
// q blocks store into [2][N][128] fp32 (slice = channel>>7).
__global__ __launch_bounds__(256) void gemm_kernel(
    const __hip_bfloat16* __restrict__ xb,   // [10000][256]
    const __hip_bfloat16* __restrict__ Wt,   // [1024][256] (this layer, col-paired)
    const float* __restrict__ biasf,         // [1024] (col-paired)
    float* __restrict__ q2,                  // [2][N][128] fp32
    unsigned short* __restrict__ kvu,        // [2][N][128] uint: k->lo, v->hi
    float* __restrict__ skip) {              // [N][256] fp32
  __shared__ __align__(16) unsigned short SH[16384];  // 32KB: As|Bs, reused for kv tile
  __hip_bfloat16* As = (__hip_bfloat16*)SH;
  __hip_bfloat16* Bs = (__hip_bfloat16*)(SH + 8192);
  int tid = threadIdx.x;
  int wid = tid >> 6, lane = tid & 63;
  int row0 = blockIdx.x * 128;
  int col0 = blockIdx.y * 128;
  int wr = wid >> 1, wc = wid & 1;
  int lr = lane & 15, lq = lane >> 4;
  int swz = (lr & 7) * 8;  // read-side XOR (elements)

  f32x4 acc[4][4] = {};

  for (int k0 = 0; k0 < C_DIM; k0 += 64) {
#pragma unroll
    for (int j = 0; j < 4; ++j) {
      int c = j * 256 + wid * 64 + lane;
      int arow = c >> 3;
      int kc = 8 * ((c & 7) ^ ((c >> 3) & 7));  // inverse-swizzled source
      int grow = row0 + arow;
      if (grow > N_NODES - 1) grow = N_NODES - 1;  // clamp: in-bounds, rows unused
      gload16(xb + (size_t)grow * C_DIM + k0 + kc, As + (size_t)(j * 256 + wid * 64) * 8);
    }
#pragma unroll
    for (int j = 0; j < 4; ++j) {
      int c = j * 256 + wid * 64 + lane;
      int brow = c >> 3;
      int kc = 8 * ((c & 7) ^ ((c >> 3) & 7));
      gload16(Wt + (size_t)(col0 + brow) * C_DIM + k0 + kc,
              Bs + (size_t)(j * 256 + wid * 64) * 8);
    }
    __syncthreads();

#pragma unroll
    for (int ks = 0; ks < 2; ++ks) {
      bf16x8 fa[4], fb[4];
#pragma unroll
      for (int m = 0; m < 4; ++m)
        fa[m] = *(const bf16x8*)&As[(wr * 64 + m * 16 + lr) * 64 + ((ks * 32 + lq * 8) ^ swz)];
#pragma unroll
      for (int n = 0; n < 4; ++n)
        fb[n] = *(const bf16x8*)&Bs[(wc * 64 + n * 16 + lr) * 64 + ((ks * 32 + lq * 8) ^ swz)];
#pragma unroll
      for (int m = 0; m < 4; ++m)
#pragma unroll
        for (int n = 0; n < 4; ++n)
          acc[m][n] = __builtin_amdgcn_mfma_f32_16x16x32_bf16(fa[m], fb[n], acc[m][n], 0, 0, 0);
    }
    __syncthreads();
  }

  float bias_n[4];
#pragma unroll
  for (int n = 0; n < 4; ++n) bias_n[n] = biasf[col0 + wc * 64 + n * 16 + lr];

  if (col0 >= 256 && col0 < 768) {
    // ---- kv path: stage interleaved k|v tile in LDS, then coalesced uint4 stores
    int half = wc;  // wc=0 -> k half, wc=1 -> v half (column pairing)
#pragma unroll
    for (int m = 0; m < 4; ++m) {
#pragma unroll
      for (int n = 0; n < 4; ++n) {
        int chs = n * 16 + lr;  // channel-in-64-block 0..63
#pragma unroll
        for (int r = 0; r < 4; ++r) {
          int row = wr * 64 + m * 16 + lq * 4 + r;
          SH[row * 128 + chs * 2 + half] = f2b(acc[m][n][r] + bias_n[n]);
        }
      }
    }
    __syncthreads();
    int bl = (col0 - 256) >> 7;       // 64-ch block 0..3
    int sl = bl >> 1;                 // slice 0..1
    int h64 = (bl & 1) * 64;          // 64-ch half within 128-ch slice
    unsigned int* kvd = (unsigned int*)kvu;
    int t16 = tid & 15, rbase = tid >> 4;
#pragma unroll
    for (int it = 0; it < 8; ++it) {
      int row = it * 16 + rbase;
      int grow = row0 + row;
      if (grow < N_NODES) {
        uint4 vv = *(const uint4*)&SH[row * 128 + t16 * 8];  // channels [4*t16,4*t16+4)
        *(uint4*)&kvd[((size_t)sl * N_NODES + grow) * 128 + h64 + t16 * 4] = vv;
      }
    }
  } else {
    // ---- q / skip scalar path
#pragma unroll
    for (int m = 0; m < 4; ++m) {
#pragma unroll
      for (int n = 0; n < 4; ++n) {
        int colG = col0 + wc * 64 + n * 16 + lr;
#pragma unroll
        for (int r = 0; r < 4; ++r) {
          int grow = row0 + wr * 64 + m * 16 + lq * 4 + r;
          if (grow < N_NODES) {
            float val = acc[m][n][r] + bias_n[n];
            if (col0 < 256) {
              q2[((size_t)(colG >> 7) * N_NODES + grow) * 128 + (colG & 127)] = val;
            } else {
              skip[(size_t)grow * C_DIM + (colG - 768)] = val;
            }
          }
        }
      }
    }
  }
}

// ---------------- per-node aggregation, no-max softmax (2x128ch slices) ----------------
// Wave = (node, 128-ch slice); slot = lane>>5 (2 edges in parallel); 4 ch/lane;
// head = 8-lane group (4 heads per slice). slice = blockIdx&1 -> slice 0 on even
// XCDs, slice 1 on odd (per-XCD kv WS 5.12MB, mostly L2-resident, LLC backstop).
// Per edge: ONE 512B gather (vs 4x256B in the 4-slice layout) -- memory-instr
// halved, VALU unchanged, bytes unchanged. Scores |s| << 87 -> softmax without
// max subtraction exact; q pre-scaled by log2e/sqrt(32), e = exp2(p).
// Depth-2 pipeline: 4 edges/iter, t+1 kv and t+2 indices in flight; 2-wide tail.
__global__ __launch_bounds__(256) void agg_kernel(
    const float* __restrict__ q2,          // [2][N][128] fp32
    const unsigned int* __restrict__ kv2,  // [2][N][128] k|v bf16 pairs
    const int* __restrict__ row_ptr, const int* __restrict__ srcs,
    float* __restrict__ out, __hip_bfloat16* __restrict__ xb_next) {
  int b = blockIdx.x;
  int slice = b & 1;
  int wid = threadIdx.x >> 6, lane = threadIdx.x & 63;
  int n = (b >> 1) * 4 + wid;
  int slot = lane >> 5;                     // 2 edge-slots per wave
  int l4 = (lane & 31) * 4;                 // 4 ch/lane, 128 ch per slice
  const size_t SB = (size_t)slice * N_NODES * 128;
  const float scl = 0.25503526f;            // log2(e)/sqrt(32)

  float4 qv = *(const float4*)&q2[SB + (size_t)n * 128 + l4];
  qv.x *= scl; qv.y *= scl; qv.z *= scl; qv.w *= scl;
  const unsigned int* kvs = kv2 + SB;

  int beg = row_ptr[n], end = row_ptr[n + 1];
  float l = 0.f;
  float4 a = make_float4(0.f, 0.f, 0.f, 0.f);

  int i = beg;
  int sa1 = 0, sb1 = 0;
  uint4 wa = make_uint4(0, 0, 0, 0), wb = make_uint4(0, 0, 0, 0);
  if (i + 4 <= end) {                       // prologue: iter0 kv + iter1 indices
    int sa0 = srcs[i + slot], sb0 = srcs[i + 2 + slot];
    wa = *(const uint4*)&kvs[(size_t)sa0 * 128 + l4];
    wb = *(const uint4*)&kvs[(size_t)sb0 * 128 + l4];
    if (i + 8 <= end) { sa1 = srcs[i + 4 + slot]; sb1 = srcs[i + 6 + slot]; }
  }
  while (i + 4 <= end) {
    uint4 na = make_uint4(0, 0, 0, 0), nb = make_uint4(0, 0, 0, 0);
    if (i + 8 <= end) {                     // issue t+1 kv (indices already resident)
      na = *(const uint4*)&kvs[(size_t)sa1 * 128 + l4];
      nb = *(const uint4*)&kvs[(size_t)sb1 * 128 + l4];
      if (i + 12 <= end) {                  // issue t+2 indices
        sa1 = srcs[i + 8 + slot]; sb1 = srcs[i + 10 + slot];
      }
    }
    float pa = red8(dot4(qv, wa));
    float pb = red8(dot4(qv, wb));
    float ea = exp2f(pa), eb = exp2f(pb);
    l += ea + eb;
    a.x = fmaf(ea, kv_hi(wa.x), fmaf(eb, kv_hi(wb.x), a.x));
    a.y = fmaf(ea, kv_hi(wa.y), fmaf(eb, kv_hi(wb.y), a.y));
    a.z = fmaf(ea, kv_hi(wa.z), fmaf(eb, kv_hi(wb.z), a.z));
    a.w = fmaf(ea, kv_hi(wa.w), fmaf(eb, kv_hi(wb.w), a.w));
    wa = na; wb = nb;
    i += 4;
  }
  for (; i < end; i += 2) {                 // guarded 2-wide tail (<= 2 iters)
    int j = i + slot;
    bool valid = j < end;
    int s = srcs[valid ? j : beg];
    uint4 w = *(const uint4*)&kvs[(size_t)s * 128 + l4];
    float p = red8(dot4(qv, w));
    float e = valid ? exp2f(p) : 0.f;
    l += e;
    a.x = fmaf(e, kv_hi(w.x), a.x);
    a.y = fmaf(e, kv_hi(w.y), a.y);
    a.z = fmaf(e, kv_hi(w.z), a.z);
    a.w = fmaf(e, kv_hi(w.w), a.w);
  }

  // merge the 2 edge-slots (pure adds; both halves get totals)
  l   += __shfl_xor(l, 32);
  a.x += __shfl_xor(a.x, 32);
  a.y += __shfl_xor(a.y, 32);
  a.z += __shfl_xor(a.z, 32);
  a.w += __shfl_xor(a.w, 32);

  if (lane < 32) {
    float inv = 1.f / (l + 1e-16f);
    size_t idx = (size_t)n * C_DIM + slice * 128 + l4;
    float4 o = *(const float4*)&out[idx];
    o.x += a.x * inv; o.y += a.y * inv; o.z += a.z * inv; o.w += a.w * inv;
    *(float4*)&out[idx] = o;
    union { unsigned short us[4]; uint2 w; } ob;
    ob.us[0] = f2b(o.x); ob.us[1] = f2b(o.y); ob.us[2] = f2b(o.z); ob.us[3] = f2b(o.w);
    *(uint2*)&xb_next[idx] = ob.w;
  }
}

extern "C" void kernel_launch(void* const* d_in, const int* in_sizes, int n_in,
                              void* d_out, int out_size, void* d_ws, size_t ws_size,
                              hipStream_t stream) {
  const float* x0 = (const float*)d_in[0];
  const float* Wq = (const float*)d_in[1];
  const float* bq = (const float*)d_in[2];
  const float* Wk = (const float*)d_in[3];
  const float* bk = (const float*)d_in[4];
  const float* Wv = (const float*)d_in[5];
  const float* bv = (const float*)d_in[6];
  const float* Ws = (const float*)d_in[7];
  const float* bs = (const float*)d_in[8];
  const int* ei  = (const int*)d_in[9];
  const int* src = ei;
  const int* dst = ei + E_EDGES;
  float* out = (float*)d_out;

  const size_t NC = (size_t)N_NODES * C_DIM;  // 2,560,000
  __hip_bfloat16* xb = (__hip_bfloat16*)d_ws;
  unsigned int* kvbuf = (unsigned int*)(xb + NC);       // [2][N][128] k|v bf16 pairs
  __hip_bfloat16* Wt = (__hip_bfloat16*)(kvbuf + NC);   // 3*1024*256
  float* qbuf  = (float*)(Wt + (size_t)L_LAYERS * GN * C_DIM);  // [2][N][128]
  float* skipA = qbuf + NC;
  float* biasf = skipA + NC;                            // 3*1024
  int* row_ptr = (int*)(biasf + L_LAYERS * GN);
  int* deg  = row_ptr + (N_NODES + 1);
  int* fill = deg + N_NODES;
  int* srcs = fill + N_NODES;

  (void)hipMemsetAsync(deg, 0, 2 * N_NODES * sizeof(int), stream);  // deg + fill
  hist_kernel<<<(E_EDGES + 255) / 256, 256, 0, stream>>>(dst, deg);
  scan_kernel<<<1, 1024, 0, stream>>>(deg, row_ptr);
  scatter_kernel<<<(E_EDGES + 255) / 256, 256, 0, stream>>>(src, dst, row_ptr, fill, srcs);

  conv_all_kernel<<<3281, 256, 0, stream>>>(x0, xb, Wq, Wk, Wv, Ws, Wt,
                                            bq, bk, bv, bs, biasf);

  for (int l = 0; l < L_LAYERS; ++l) {
    float* skip = (l == L_LAYERS - 1) ? out : skipA;
    gemm_kernel<<<dim3((N_NODES + 127) / 128, GN / 128), 256, 0, stream>>>(
        xb, Wt + (size_t)l * GN * C_DIM, biasf + l * GN, qbuf,
        (unsigned short*)kvbuf, skip);
    agg_kernel<<<dim3(2 * (N_NODES / 4)), 256, 0, stream>>>(
        qbuf, kvbuf, row_ptr, srcs, skip, xb);
  }
}